// Round 21
// baseline (170.144 us; speedup 1.0000x reference)
//
#include <hip/hip_runtime.h>
#include <hip/hip_bf16.h>
#include <math.h>

// Problem constants
#define BB 2
#define CC 64
#define HH 256
#define WW 256
#define OO 64
#define K2 9
#define HW 65536
#define CHW (CC*HW)

typedef _Float16 h8 __attribute__((ext_vector_type(8)));
typedef __fp16 fp16x2 __attribute__((ext_vector_type(2)));
typedef __attribute__((ext_vector_type(4))) unsigned int ux4;
typedef __attribute__((ext_vector_type(4))) float f32x4;

// Bijective XCD swizzle (nwg divisible by 8)
__device__ __forceinline__ int xcd_swz(int bid, int nwg) {
    const int per = nwg >> 3;
    return (bid & 7) * per + (bid >> 3);
}
__device__ __forceinline__ unsigned short f2h(float f) {
    _Float16 h = (_Float16)f;
    return __builtin_bit_cast(unsigned short, h);
}
__device__ __forceinline__ unsigned int pkrtz(float lo, float hi) {
    fp16x2 p = __builtin_amdgcn_cvt_pkrtz(lo, hi);
    return __builtin_bit_cast(unsigned int, p);
}
__device__ __forceinline__ h8 splat8(float f) {
    _Float16 h = (_Float16)f;
    h8 r = {h, h, h, h, h, h, h, h};
    return r;
}

// wA: [32 ch][576 s'] fp16, s' = tap*64 + c (tap-major K order). rows 27..31 = 0.
// wk: [9 k][64 o][64 c] fp16.
__global__ __launch_bounds__(256) void k_prep(
    const float* __restrict__ offw, const float* __restrict__ ampw,
    const float* __restrict__ w3d,
    unsigned short* __restrict__ wA, unsigned short* __restrict__ wk)
{
    int i = blockIdx.x * 256 + threadIdx.x;   // grid 216 -> 55296 exact
    if (i < 18432) {
        int ch = i / 576, sp = i % 576;
        int tap = sp >> 6, c = sp & 63;
        float v = 0.f;
        if (ch < 18)      v = offw[ch*576 + c*9 + tap];
        else if (ch < 27) v = ampw[(ch-18)*576 + c*9 + tap];
        wA[i] = f2h(v);
    } else if (i < 55296) {
        int j = i - 18432;
        int k = j >> 12, rem = j & 4095;
        int o = rem >> 6, c = rem & 63;
        wk[j] = f2h(w3d[o*576 + c*9 + k]);
    }
}

// Fused kernel, tap-split. Block = 512 thr = 8 waves, owns (b, h, 64-px
// quarter-row), all 64 o. Wave w: px-group g = w&3, tap-half = w>>2
// (taps 0-4 / 5-8). Tile = 5 rows x 68 cols fp16 (43.5 KB) -> 3 blocks/CU.
// Conv computed redundantly per wave-pair (no cross-wave comm); halves summed
// via LDS (overlaid on dead tile) at the end.
__global__ __launch_bounds__(512) void k_fused(
    const float* __restrict__ x, const unsigned short* __restrict__ wA,
    const unsigned short* __restrict__ wk,
    const float* __restrict__ offb, const float* __restrict__ ampb,
    float* __restrict__ out)
{
    // LDS: tile fp16, 340 planes (pp = rr*68+cc) x 128B (64 c), 16B-slot
    // XOR-swizzled by (pp&7). After phase 3 the tile is dead; the first
    // 16 KB are reused as the f32 reduction buffer.
    __shared__ __attribute__((aligned(16))) unsigned char lds[43520];
    unsigned char* tb = lds;
    float* red = (float*)lds;       // [16 slots][256] f32, strided conflict-free

    const int tid = threadIdx.x;
    const int idx = xcd_swz(blockIdx.x, BB*HH*4);       // 2048 blocks
    const int wq = idx & 3, h = (idx >> 2) & 255, b = idx >> 10;
    const int w0 = wq << 6;
    const int lane = tid & 63, wv = tid >> 6;
    const int lrow = lane & 15, lg = lane >> 4;
    const int g = wv & 3;           // px group (16 px)
    const int half = wv >> 2;       // tap half: 0 -> taps 0..4, 1 -> taps 5..8

    const float* xb = x + (size_t)b * CHW;
    const int r0a = h - 2, c0a = w0 - 2;

    // ---- Phase 1: stage tile (abs rows h-2..h+2, cols w0-2..w0+65, 0 outside).
    if (tid < 340) {
        const int rr = tid / 68;
        const int cc = tid - rr*68;
        const int ra = r0a + rr, ca = c0a + cc;
        const bool inb = ((unsigned)ra < 256u) && ((unsigned)ca < 256u);
        const float* ps = xb + ra*256 + ca;
        const int swz = (tid & 7) << 4;
#pragma unroll
        for (int ch = 0; ch < 64; ch += 16) {
            float v[16];
#pragma unroll
            for (int j = 0; j < 16; ++j)
                v[j] = inb ? ps[(size_t)(ch + j) * HW] : 0.f;
            ux4 q0, q1;
            q0[0] = pkrtz(v[0],  v[1]);
            q0[1] = pkrtz(v[2],  v[3]);
            q0[2] = pkrtz(v[4],  v[5]);
            q0[3] = pkrtz(v[6],  v[7]);
            q1[0] = pkrtz(v[8],  v[9]);
            q1[1] = pkrtz(v[10], v[11]);
            q1[2] = pkrtz(v[12], v[13]);
            q1[3] = pkrtz(v[14], v[15]);
            *(ux4*)(tb + tid*128 + ((ch*2     ) ^ swz)) = q0;
            *(ux4*)(tb + tid*128 + ((ch*2 + 16) ^ swz)) = q1;
        }
    }
    __syncthreads();

    // ---- Phase 2: offset/amp conv via MFMA (fp16), redundantly per wave-pair.
    // D[m=ch(32)][n=px(16)] for px group g. Params via verified shfl mapping.
    unsigned int pk_oyx[K2];
    float aav[K2];
    {
        f32x4 o0 = {0.f,0.f,0.f,0.f}, o1 = {0.f,0.f,0.f,0.f};
        const int pxl = g*16 + lrow;            // 0..63
#pragma unroll
        for (int ks = 0; ks < 18; ++ks) {
            const int sbase = ks*32 + lg*8;
            const int tap = sbase >> 6;
            const int cb  = sbase & 63;
            const int ky = tap / 3, kx = tap - ky*3;
            const int pp = (ky + 1)*68 + pxl + kx + 1;
            const h8 bf = *(const h8*)(tb + pp*128 + ((2*cb) ^ ((pp & 7) << 4)));
            const h8 a0 = *(const h8*)(wA + (      lrow)*576 + sbase);
            const h8 a1 = *(const h8*)(wA + (16 + lrow)*576 + sbase);
            o0 = __builtin_amdgcn_mfma_f32_16x16x32_f16(a0, bf, o0, 0, 0, 0);
            o1 = __builtin_amdgcn_mfma_f32_16x16x32_f16(a1, bf, o1, 0, 0, 0);
        }
        // D col=px(lane&15), row=ch((lane>>4)*4+r)
#pragma unroll
        for (int k = 0; k < K2; ++k) {
            const int cy = 2*k, cx = 2*k + 1, ca = 18 + k;
            const float vy = (cy < 16)
                ? __shfl(o0[cy & 3], lrow | ((cy >> 2) << 4), 64)
                : __shfl(o1[(cy - 16) & 3], lrow | (((cy - 16) >> 2) << 4), 64);
            const float vx = (cx < 16)
                ? __shfl(o0[cx & 3], lrow | ((cx >> 2) << 4), 64)
                : __shfl(o1[(cx - 16) & 3], lrow | (((cx - 16) >> 2) << 4), 64);
            const float va = __shfl(o1[(ca - 16) & 3], lrow | (((ca - 16) >> 2) << 4), 64);
            pk_oyx[k] = pkrtz(vy + offb[cy], vx + offb[cx]);
            aav[k] = 1.f / (1.f + __expf(-(va + ampb[k])));
        }
    }

    // ---- Phase 3: this wave's tap subset only (4 or 5 taps).
    const int pxl = g*16 + lrow;          // this thread's A-row pixel (0..63)
    const int cA0 = lg*8;                 // fallback c-chunk bases
    const int cA1 = 32 + lg*8;
    const int cb0 = lg*16;                // byte offsets within a 128B plane
    const int cb1 = 64 + lg*16;

    f32x4 acc[4];
#pragma unroll
    for (int n = 0; n < 4; ++n) acc[n] = (f32x4){0.f, 0.f, 0.f, 0.f};

    auto tap_body = [&](int k) {
        // B-fragments for tap k, directly from global (L2-resident 8KB slice)
        h8 bf0[4], bf1[4];
        {
            const unsigned short* wb = wk + (size_t)k*4096 + lg*8;
#pragma unroll
            for (int n = 0; n < 4; ++n) {
                bf0[n] = *(const h8*)(wb + (n*16 + lrow)*64);
                bf1[n] = *(const h8*)(wb + (n*16 + lrow)*64 + 32);
            }
        }

        const fp16x2 oyx = __builtin_bit_cast(fp16x2, pk_oyx[k]);
        const int ky = k / 3, kx = k - ky*3;
        const float aa = aav[k];
        float yy = (float)(h + ky) + (float)oyx[0];
        float xx = (float)(w0 + pxl + kx) + (float)oyx[1];
        yy = fminf(fmaxf(yy, 0.f), 257.f);
        xx = fminf(fmaxf(xx, 0.f), 257.f);

        const float y0f = floorf(yy), x0f = floorf(xx);
        const float y1f = fminf(y0f + 1.f, 257.f);
        const float x1f = fminf(x0f + 1.f, 257.f);
        const float ay = yy - y0f, by = y1f - yy;
        const float ax = xx - x0f, bx = x1f - xx;
        const int r0 = (int)y0f - 1, r1 = (int)y1f - 1;
        const int c0 = (int)x0f - 1, c1 = (int)x1f - 1;
        const int rr0 = r0 - r0a, rr1 = r1 - r0a;
        const int cc0 = c0 - c0a, cc1 = c1 - c0a;
        const float w00 = by*bx*aa, w01 = by*ax*aa, w10 = ay*bx*aa, w11 = ay*ax*aa;

        h8 A0, A1;
        const bool ok = ((unsigned)rr0 <= 4u) && ((unsigned)rr1 <= 4u) &&
                        ((unsigned)cc0 <= 67u) && ((unsigned)cc1 <= 67u);
        if (ok) {
            const int pp00 = rr0*68 + cc0, pp01 = rr0*68 + cc1;
            const int pp10 = rr1*68 + cc0, pp11 = rr1*68 + cc1;
            const int s00 = (pp00 & 7) << 4, s01 = (pp01 & 7) << 4;
            const int s10 = (pp10 & 7) << 4, s11 = (pp11 & 7) << 4;
            const h8 Wb00 = splat8(w00), Wb01 = splat8(w01);
            const h8 Wb10 = splat8(w10), Wb11 = splat8(w11);

            const h8 d00a = *(const h8*)(tb + pp00*128 + (cb0 ^ s00));
            const h8 d01a = *(const h8*)(tb + pp01*128 + (cb0 ^ s01));
            const h8 d10a = *(const h8*)(tb + pp10*128 + (cb0 ^ s10));
            const h8 d11a = *(const h8*)(tb + pp11*128 + (cb0 ^ s11));
            const h8 d00b = *(const h8*)(tb + pp00*128 + (cb1 ^ s00));
            const h8 d01b = *(const h8*)(tb + pp01*128 + (cb1 ^ s01));
            const h8 d10b = *(const h8*)(tb + pp10*128 + (cb1 ^ s10));
            const h8 d11b = *(const h8*)(tb + pp11*128 + (cb1 ^ s11));

            h8 t = d00a * Wb00;
            t = __builtin_elementwise_fma(d01a, Wb01, t);
            t = __builtin_elementwise_fma(d10a, Wb10, t);
            t = __builtin_elementwise_fma(d11a, Wb11, t);
            A0 = t;
            h8 u = d00b * Wb00;
            u = __builtin_elementwise_fma(d01b, Wb01, u);
            u = __builtin_elementwise_fma(d10b, Wb10, u);
            u = __builtin_elementwise_fma(d11b, Wb11, u);
            A1 = u;
        } else {
            const bool vy0 = (unsigned)r0 < 256u, vy1 = (unsigned)r1 < 256u;
            const bool vx0 = (unsigned)c0 < 256u, vx1 = (unsigned)c1 < 256u;
            float W00 = w00, W01 = w01, W10 = w10, W11 = w11;
            int o00, o01, o10, o11;
            if (vy0 && vx0) o00 = r0*WW + c0; else { o00 = 0; W00 = 0.f; }
            if (vy0 && vx1) o01 = r0*WW + c1; else { o01 = 0; W01 = 0.f; }
            if (vy1 && vx0) o10 = r1*WW + c0; else { o10 = 0; W10 = 0.f; }
            if (vy1 && vx1) o11 = r1*WW + c1; else { o11 = 0; W11 = 0.f; }
            const float* pc0 = xb + (size_t)cA0 * HW;
            const float* pc1 = xb + (size_t)cA1 * HW;
#pragma unroll
            for (int jj = 0; jj < 8; ++jj) {
                float va = W00*pc0[o00] + W01*pc0[o01] + W10*pc0[o10] + W11*pc0[o11];
                pc0 += HW;
                A0[jj] = (_Float16)va;
                float vb = W00*pc1[o00] + W01*pc1[o01] + W10*pc1[o10] + W11*pc1[o11];
                pc1 += HW;
                A1[jj] = (_Float16)vb;
            }
        }

#pragma unroll
        for (int n = 0; n < 4; ++n)
            acc[n] = __builtin_amdgcn_mfma_f32_16x16x32_f16(A0, bf0[n], acc[n], 0, 0, 0);
#pragma unroll
        for (int n = 0; n < 4; ++n)
            acc[n] = __builtin_amdgcn_mfma_f32_16x16x32_f16(A1, bf1[n], acc[n], 0, 0, 0);
    };

    if (half == 0) {
#pragma unroll
        for (int k = 0; k < 5; ++k) tap_body(k);
    } else {
#pragma unroll
        for (int k = 5; k < K2; ++k) tap_body(k);
    }

    // ---- Combine halves: tile is dead; reuse first 16 KB as f32 buffer.
    __syncthreads();        // all sampling reads of tb complete
    if (half == 1) {
#pragma unroll
        for (int n = 0; n < 4; ++n)
#pragma unroll
            for (int r = 0; r < 4; ++r)
                red[(n*4 + r)*256 + g*64 + lane] = acc[n][r];  // conflict-free
    }
    __syncthreads();

    if (half == 0) {
        const size_t ob = (size_t)b*OO*HW + (size_t)h*WW + w0 + g*16 + lg*4;
#pragma unroll
        for (int n = 0; n < 4; ++n) {
            f32x4 v;
#pragma unroll
            for (int r = 0; r < 4; ++r)
                v[r] = fmaxf(acc[n][r] + red[(n*4 + r)*256 + g*64 + lane], 0.f);
            *(f32x4*)(out + ob + (size_t)(n*16 + lrow)*HW) = v;
        }
    }
}

extern "C" void kernel_launch(void* const* d_in, const int* in_sizes, int n_in,
                              void* d_out, int out_size, void* d_ws, size_t ws_size,
                              hipStream_t stream) {
    const float* x    = (const float*)d_in[0];
    const float* offw = (const float*)d_in[1];
    const float* offb = (const float*)d_in[2];
    const float* ampw = (const float*)d_in[3];
    const float* ampb = (const float*)d_in[4];
    const float* w3d  = (const float*)d_in[5];
    float* out = (float*)d_out;

    unsigned short* wA = (unsigned short*)d_ws;          // 18432 fp16
    unsigned short* wk = wA + 18432;                     // 36864 fp16

    k_prep<<<216, 256, 0, stream>>>(offw, ampw, w3d, wA, wk);
    k_fused<<<BB*HH*4, 512, 0, stream>>>(x, wA, wk, offb, ampb, out);
}

// Round 22
// 118.567 us; speedup vs baseline: 1.4350x; 1.4350x over previous
//
#include <hip/hip_runtime.h>
#include <hip/hip_bf16.h>
#include <math.h>

// Problem constants
#define BB 2
#define CC 64
#define HH 256
#define WW 256
#define OO 64
#define K2 9
#define HW 65536
#define CHW (CC*HW)

typedef _Float16 h8 __attribute__((ext_vector_type(8)));
typedef __fp16 fp16x2 __attribute__((ext_vector_type(2)));
typedef __attribute__((ext_vector_type(4))) unsigned int ux4;
typedef __attribute__((ext_vector_type(4))) float f32x4;

// Bijective XCD swizzle (nwg divisible by 8)
__device__ __forceinline__ int xcd_swz(int bid, int nwg) {
    const int per = nwg >> 3;
    return (bid & 7) * per + (bid >> 3);
}
__device__ __forceinline__ unsigned short f2h(float f) {
    _Float16 h = (_Float16)f;
    return __builtin_bit_cast(unsigned short, h);
}
__device__ __forceinline__ unsigned int pkrtz(float lo, float hi) {
    fp16x2 p = __builtin_amdgcn_cvt_pkrtz(lo, hi);
    return __builtin_bit_cast(unsigned int, p);
}
__device__ __forceinline__ h8 splat8(float f) {
    _Float16 h = (_Float16)f;
    h8 r = {h, h, h, h, h, h, h, h};
    return r;
}

// wA: [32 ch][576 s'] fp16, s' = tap*64 + c (tap-major K order). rows 27..31 = 0.
// wk: [9 k][64 o][64 c] fp16.
__global__ __launch_bounds__(256) void k_prep(
    const float* __restrict__ offw, const float* __restrict__ ampw,
    const float* __restrict__ w3d,
    unsigned short* __restrict__ wA, unsigned short* __restrict__ wk)
{
    int i = blockIdx.x * 256 + threadIdx.x;   // grid 216 -> 55296 exact
    if (i < 18432) {
        int ch = i / 576, sp = i % 576;
        int tap = sp >> 6, c = sp & 63;
        float v = 0.f;
        if (ch < 18)      v = offw[ch*576 + c*9 + tap];
        else if (ch < 27) v = ampw[(ch-18)*576 + c*9 + tap];
        wA[i] = f2h(v);
    } else if (i < 55296) {
        int j = i - 18432;
        int k = j >> 12, rem = j & 4095;
        int o = rem >> 6, c = rem & 63;
        wk[j] = f2h(w3d[o*576 + c*9 + k]);
    }
}

// Fused kernel. Block = 512 thr = 8 waves, owns (b, row-pair h0/h0+1, 64-col
// quarter), all 64 o. LDS = tile ONLY (52,224 B). Conv params via __shfl;
// ONE barrier; direct float4 stores.
__global__ __launch_bounds__(512) void k_fused(
    const float* __restrict__ x, const unsigned short* __restrict__ wA,
    const unsigned short* __restrict__ wk,
    const float* __restrict__ offb, const float* __restrict__ ampb,
    float* __restrict__ out)
{
    __shared__ __attribute__((aligned(16))) unsigned char lds[52224];
    unsigned char* tb = lds;

    const int tid = threadIdx.x;
    const int idx = xcd_swz(blockIdx.x, BB*(HH/2)*4);   // 1024 blocks
    const int wq = idx & 3, hp = (idx >> 2) & 127, b = idx >> 9;
    const int h0 = hp << 1, w0 = wq << 6;
    const int lane = tid & 63, wv = tid >> 6;
    const int lrow = lane & 15, lg = lane >> 4;

    const float* xb = x + (size_t)b * CHW;
    const int r0a = h0 - 2, c0a = w0 - 2;

    // ---- Phase 1: stage tile (abs rows h0-2..h0+3, cols w0-2..w0+65, 0 outside).
    if (tid < 408) {
        const int rr = tid / 68;
        const int cc = tid - rr*68;
        const int ra = r0a + rr, ca = c0a + cc;
        const bool inb = ((unsigned)ra < 256u) && ((unsigned)ca < 256u);
        const float* ps = xb + ra*256 + ca;
        const int swz = (tid & 7) << 4;
#pragma unroll
        for (int ch = 0; ch < 64; ch += 16) {
            float v[16];
#pragma unroll
            for (int j = 0; j < 16; ++j)
                v[j] = inb ? ps[(size_t)(ch + j) * HW] : 0.f;
            ux4 q0, q1;
            q0[0] = pkrtz(v[0],  v[1]);
            q0[1] = pkrtz(v[2],  v[3]);
            q0[2] = pkrtz(v[4],  v[5]);
            q0[3] = pkrtz(v[6],  v[7]);
            q1[0] = pkrtz(v[8],  v[9]);
            q1[1] = pkrtz(v[10], v[11]);
            q1[2] = pkrtz(v[12], v[13]);
            q1[3] = pkrtz(v[14], v[15]);
            *(ux4*)(tb + tid*128 + ((ch*2     ) ^ swz)) = q0;
            *(ux4*)(tb + tid*128 + ((ch*2 + 16) ^ swz)) = q1;
        }
    }
    __syncthreads();      // the ONLY barrier: tile is read-only afterwards

    // ---- Phase 2: offset/amp conv via MFMA (fp16). D[m=ch(32)][n=px(16/wave)].
    unsigned int pk_oyx[K2];
    float aav[K2];
    {
        f32x4 o0 = {0.f,0.f,0.f,0.f}, o1 = {0.f,0.f,0.f,0.f};
        const int pxl = wv*16 + lrow;           // 0..127
        const int prow2 = pxl >> 6, pcol2 = pxl & 63;
#pragma unroll
        for (int ks = 0; ks < 18; ++ks) {
            const int sbase = ks*32 + lg*8;
            const int tap = sbase >> 6;
            const int cb  = sbase & 63;
            const int ky = tap / 3, kx = tap - ky*3;
            const int pp = (prow2 + ky + 1)*68 + pcol2 + kx + 1;
            const h8 bf = *(const h8*)(tb + pp*128 + ((2*cb) ^ ((pp & 7) << 4)));
            const h8 a0 = *(const h8*)(wA + (      lrow)*576 + sbase);
            const h8 a1 = *(const h8*)(wA + (16 + lrow)*576 + sbase);
            o0 = __builtin_amdgcn_mfma_f32_16x16x32_f16(a0, bf, o0, 0, 0, 0);
            o1 = __builtin_amdgcn_mfma_f32_16x16x32_f16(a1, bf, o1, 0, 0, 0);
        }
        // D col=px(lane&15), row=ch((lane>>4)*4+r)
#pragma unroll
        for (int k = 0; k < K2; ++k) {
            const int cy = 2*k, cx = 2*k + 1, ca = 18 + k;
            const float vy = (cy < 16)
                ? __shfl(o0[cy & 3], lrow | ((cy >> 2) << 4), 64)
                : __shfl(o1[(cy - 16) & 3], lrow | (((cy - 16) >> 2) << 4), 64);
            const float vx = (cx < 16)
                ? __shfl(o0[cx & 3], lrow | ((cx >> 2) << 4), 64)
                : __shfl(o1[(cx - 16) & 3], lrow | (((cx - 16) >> 2) << 4), 64);
            const float va = __shfl(o1[(ca - 16) & 3], lrow | (((ca - 16) >> 2) << 4), 64);
            pk_oyx[k] = pkrtz(vy + offb[cy], vx + offb[cx]);
            aav[k] = 1.f / (1.f + __expf(-(va + ampb[k])));
        }
    }

    // ---- Phase 3: fully-unrolled tap loop; head is register-only.
    const int px = wv*16 + lrow;          // this thread's A-row pixel (0..127)
    const int prow = px >> 6, pcol = px & 63;
    const int cA0 = lg*8;                 // fallback c-chunk bases
    const int cA1 = 32 + lg*8;
    const int cb0 = lg*16;                // byte offsets within a 128B plane
    const int cb1 = 64 + lg*16;

    f32x4 acc[4];
#pragma unroll
    for (int n = 0; n < 4; ++n) acc[n] = (f32x4){0.f, 0.f, 0.f, 0.f};

#pragma unroll
    for (int k = 0; k < K2; ++k) {
        // B-fragments for tap k, directly from global (L2-resident 8KB slice)
        h8 bf0[4], bf1[4];
        {
            const unsigned short* wb = wk + (size_t)k*4096 + lg*8;
#pragma unroll
            for (int n = 0; n < 4; ++n) {
                bf0[n] = *(const h8*)(wb + (n*16 + lrow)*64);
                bf1[n] = *(const h8*)(wb + (n*16 + lrow)*64 + 32);
            }
        }

        // sampling params (registers only)
        const fp16x2 oyx = __builtin_bit_cast(fp16x2, pk_oyx[k]);
        const int ky = k / 3, kx = k - ky*3;
        const float aa = aav[k];
        float yy = (float)(h0 + prow + ky) + (float)oyx[0];
        float xx = (float)(w0 + pcol + kx) + (float)oyx[1];
        yy = fminf(fmaxf(yy, 0.f), 257.f);
        xx = fminf(fmaxf(xx, 0.f), 257.f);

        const float y0f = floorf(yy), x0f = floorf(xx);
        const float y1f = fminf(y0f + 1.f, 257.f);
        const float x1f = fminf(x0f + 1.f, 257.f);
        const float ay = yy - y0f, by = y1f - yy;
        const float ax = xx - x0f, bx = x1f - xx;
        const int r0 = (int)y0f - 1, r1 = (int)y1f - 1;
        const int c0 = (int)x0f - 1, c1 = (int)x1f - 1;
        const int rr0 = r0 - r0a, rr1 = r1 - r0a;
        const int cc0 = c0 - c0a, cc1 = c1 - c0a;
        const float w00 = by*bx*aa, w01 = by*ax*aa, w10 = ay*bx*aa, w11 = ay*ax*aa;

        h8 A0, A1;
        const bool ok = ((unsigned)rr0 <= 5u) && ((unsigned)rr1 <= 5u) &&
                        ((unsigned)cc0 <= 67u) && ((unsigned)cc1 <= 67u);
        if (ok) {
            const int pp00 = rr0*68 + cc0, pp01 = rr0*68 + cc1;
            const int pp10 = rr1*68 + cc0, pp11 = rr1*68 + cc1;
            const int s00 = (pp00 & 7) << 4, s01 = (pp01 & 7) << 4;
            const int s10 = (pp10 & 7) << 4, s11 = (pp11 & 7) << 4;
            const h8 Wb00 = splat8(w00), Wb01 = splat8(w01);
            const h8 Wb10 = splat8(w10), Wb11 = splat8(w11);

            auto bilerp8 = [&](int off) -> h8 {
                const h8 d00 = *(const h8*)(tb + pp00*128 + (off ^ s00));
                const h8 d01 = *(const h8*)(tb + pp01*128 + (off ^ s01));
                const h8 d10 = *(const h8*)(tb + pp10*128 + (off ^ s10));
                const h8 d11 = *(const h8*)(tb + pp11*128 + (off ^ s11));
                h8 t = d00 * Wb00;
                t = __builtin_elementwise_fma(d01, Wb01, t);
                t = __builtin_elementwise_fma(d10, Wb10, t);
                t = __builtin_elementwise_fma(d11, Wb11, t);
                return t;
            };
            A0 = bilerp8(cb0);
            A1 = bilerp8(cb1);
        } else {
            const bool vy0 = (unsigned)r0 < 256u, vy1 = (unsigned)r1 < 256u;
            const bool vx0 = (unsigned)c0 < 256u, vx1 = (unsigned)c1 < 256u;
            float W00 = w00, W01 = w01, W10 = w10, W11 = w11;
            int o00, o01, o10, o11;
            if (vy0 && vx0) o00 = r0*WW + c0; else { o00 = 0; W00 = 0.f; }
            if (vy0 && vx1) o01 = r0*WW + c1; else { o01 = 0; W01 = 0.f; }
            if (vy1 && vx0) o10 = r1*WW + c0; else { o10 = 0; W10 = 0.f; }
            if (vy1 && vx1) o11 = r1*WW + c1; else { o11 = 0; W11 = 0.f; }
            const float* pc0 = xb + (size_t)cA0 * HW;
            const float* pc1 = xb + (size_t)cA1 * HW;
#pragma unroll
            for (int jj = 0; jj < 8; ++jj) {
                float va = W00*pc0[o00] + W01*pc0[o01] + W10*pc0[o10] + W11*pc0[o11];
                pc0 += HW;
                A0[jj] = (_Float16)va;
                float vb = W00*pc1[o00] + W01*pc1[o01] + W10*pc1[o10] + W11*pc1[o11];
                pc1 += HW;
                A1[jj] = (_Float16)vb;
            }
        }

        // MFMA tap k
#pragma unroll
        for (int n = 0; n < 4; ++n)
            acc[n] = __builtin_amdgcn_mfma_f32_16x16x32_f16(A0, bf0[n], acc[n], 0, 0, 0);
#pragma unroll
        for (int n = 0; n < 4; ++n)
            acc[n] = __builtin_amdgcn_mfma_f32_16x16x32_f16(A1, bf1[n], acc[n], 0, 0, 0);
    }

    // ---- Epilogue: direct coalesced float4 ReLU stores
    // acc[n][r] = D[o = n*16+lrow][p = wv*16 + lg*4 + r], p -> (row p>>6, col p&63)
    const int prow_s = wv >> 2;
    const int pcol_s = (wv & 3)*16 + lg*4;
    const size_t ob = (size_t)b*OO*HW + (size_t)(h0 + prow_s)*WW + w0 + pcol_s;
#pragma unroll
    for (int n = 0; n < 4; ++n) {
        f32x4 v;
        v[0] = fmaxf(acc[n][0], 0.f);
        v[1] = fmaxf(acc[n][1], 0.f);
        v[2] = fmaxf(acc[n][2], 0.f);
        v[3] = fmaxf(acc[n][3], 0.f);
        *(f32x4*)(out + ob + (size_t)(n*16 + lrow)*HW) = v;
    }
}

extern "C" void kernel_launch(void* const* d_in, const int* in_sizes, int n_in,
                              void* d_out, int out_size, void* d_ws, size_t ws_size,
                              hipStream_t stream) {
    const float* x    = (const float*)d_in[0];
    const float* offw = (const float*)d_in[1];
    const float* offb = (const float*)d_in[2];
    const float* ampw = (const float*)d_in[3];
    const float* ampb = (const float*)d_in[4];
    const float* w3d  = (const float*)d_in[5];
    float* out = (float*)d_out;

    unsigned short* wA = (unsigned short*)d_ws;          // 18432 fp16
    unsigned short* wk = wA + 18432;                     // 36864 fp16

    k_prep<<<216, 256, 0, stream>>>(offw, ampw, w3d, wA, wk);
    k_fused<<<BB*(HH/2)*4, 512, 0, stream>>>(x, wA, wk, offb, ampb, out);
}